// Round 7
// baseline (666.150 us; speedup 1.0000x reference)
//
#include <hip/hip_runtime.h>
#include <math.h>

#define NN 50000
#define RR 8
#define EE 800000
#define RN 400000            // RR * NN
#define DIN 128
#define K1 1024              // RR * DIN
#define KTOT 1152            // K1 + DIN
#define NBLK 391             // ceil(RN / 1024)

// ---------------- workspace layout (bytes) ----------------
#define OFF_U    0UL           // u bf16: [RN][128]            = 102,400,000
#define OFF_HB0  102400000UL   // h bf16: [NN][128]            =  12,800,000
#define OFF_HB1  115200000UL   // h bf16: [NN][128]            =  12,800,000
#define OFF_XB   128000000UL   // x bf16: [NN][128]            =  12,800,000
#define OFF_LG   140800000UL   // logits f32: [NN][64]         =  12,800,000
#define OFF_WT   153600000UL   // W^T bf16: 4 x 147456 elems   =   1,179,648
#define OFF_OFFS 154780160UL   // offsets: (RN+1) ints         =   1,600,128
#define OFF_CUR  156380288UL   // cursor/hist: RN ints         =   1,600,000
#define OFF_SRT  157980288UL   // sorted_src: EE ints          =   3,200,000
#define OFF_BS   161180288UL   // block sums                   =       4,096
#define WS_NEED  161184384UL

typedef short bf16x8 __attribute__((ext_vector_type(8)));
typedef float f32x4 __attribute__((ext_vector_type(4)));

__device__ __forceinline__ unsigned f2bf(float f) {       // RNE f32 -> bf16 bits
    unsigned x = __float_as_uint(f);
    return (x + 0x7fffu + ((x >> 16) & 1u)) >> 16;
}
__device__ __forceinline__ float bflo(unsigned p) { return __uint_as_float(p << 16); }
__device__ __forceinline__ float bfhi(unsigned p) { return __uint_as_float(p & 0xffff0000u); }

// ---------------- one-time converts ----------------
__global__ void k_cvt(const float* __restrict__ x, ushort* __restrict__ xb) {
    int i = blockIdx.x * 256 + threadIdx.x;
    if (i >= NN * 32) return;                 // float4 granules
    float4 v = ((const float4*)x)[i];
    ushort4 o;
    o.x = (ushort)f2bf(v.x); o.y = (ushort)f2bf(v.y);
    o.z = (ushort)f2bf(v.z); o.w = (ushort)f2bf(v.w);
    ((ushort4*)xb)[i] = o;
}

// build W^T[o][k] bf16, k in [0,1152): k<1024 -> W[k>>7][k&127][o], else root[k-1024][o]
__global__ void k_wt(const float* __restrict__ W, const float* __restrict__ Rt,
                     ushort* __restrict__ WT, int O) {
    int o = blockIdx.x;
    for (int k = threadIdx.x; k < KTOT; k += 256) {
        float v = (k < K1)
            ? W[(size_t)(k >> 7) * 128 * O + (size_t)(k & 127) * O + o]
            : Rt[(size_t)(k - K1) * O + o];
        WT[(size_t)o * KTOT + k] = (ushort)f2bf(v);
    }
}

// ---------------- edge preprocessing (counting sort by s = dst*8 + r) ----------------
__global__ void k_hist(const int* __restrict__ ei, const int* __restrict__ et,
                       int* __restrict__ hist) {
    int e = blockIdx.x * blockDim.x + threadIdx.x;
    if (e >= EE) return;
    atomicAdd(&hist[ei[EE + e] * RR + et[e]], 1);
}

__global__ void k_scan1(const int* __restrict__ hist, int* __restrict__ offs,
                        int* __restrict__ bsums) {
    __shared__ int tmp[1024];
    int tid = threadIdx.x;
    int g = blockIdx.x * 1024 + tid;
    int v = (g < RN) ? hist[g] : 0;
    tmp[tid] = v;
    __syncthreads();
    for (int off = 1; off < 1024; off <<= 1) {
        int t = tmp[tid];
        if (tid >= off) t += tmp[tid - off];
        __syncthreads();
        tmp[tid] = t;
        __syncthreads();
    }
    if (g < RN) offs[g] = tmp[tid] - v;
    if (tid == 1023) bsums[blockIdx.x] = tmp[1023];
}

__global__ void k_scan2(int* __restrict__ bsums) {
    __shared__ int tmp[1024];
    int tid = threadIdx.x;
    int v = (tid < NBLK) ? bsums[tid] : 0;
    tmp[tid] = v;
    __syncthreads();
    for (int off = 1; off < 1024; off <<= 1) {
        int t = tmp[tid];
        if (tid >= off) t += tmp[tid - off];
        __syncthreads();
        tmp[tid] = t;
        __syncthreads();
    }
    if (tid < NBLK) bsums[tid] = tmp[tid] - v;
}

__global__ void k_scan3(int* __restrict__ offs, const int* __restrict__ bsums) {
    int g = blockIdx.x * 1024 + threadIdx.x;
    if (g < RN) offs[g] += bsums[blockIdx.x];
    else if (g == RN) offs[RN] = EE;
}

__global__ void k_scatter(const int* __restrict__ ei, const int* __restrict__ et,
                          const int* __restrict__ offs, int* __restrict__ cur,
                          int* __restrict__ ssrc) {
    int e = blockIdx.x * blockDim.x + threadIdx.x;
    if (e >= EE) return;
    int s = ei[EE + e] * RR + et[e];
    ssrc[offs[s] + atomicAdd(&cur[s], 1)] = ei[e];
}

// ---------------- per-layer segment mean aggregation ----------------
// wave <-> node; all 8 segments of node n are contiguous in ssrc.
// One coalesced ssrc read into registers; edge srcs broadcast via __shfl.
// SAFETY INVARIANT (ds_bpermute returns UNDEFINED from exec=0 lanes): every
// __shfl here executes at FULL wave exec — the edge loop trip count is
// wave-uniform (max over the half-wave pair), shfl indices are clamped to
// [0,63], and per-lane validity only guards the VALU accumulates.
__global__ __launch_bounds__(256) void k_agg(const ushort* __restrict__ hb,
        const int* __restrict__ offs, const int* __restrict__ ssrc,
        ushort* __restrict__ u) {
    int gt = blockIdx.x * 256 + threadIdx.x;
    int wid = gt >> 6, lane = gt & 63;
    int nw = (gridDim.x * 256) >> 6;
    int half = lane >> 5;                    // 0/1: which segment of the pair
    int sub = lane & 31;                     // cols [4*sub, 4*sub+4)
    const uint2* h4 = (const uint2*)hb;
    uint2* u4 = (uint2*)u;

    if (wid >= NN) return;                   // wave-uniform
    int b_cur = offs[wid * 8 + min(lane, 8)];
    for (int n = wid; n < NN; n += nw) {     // wave-uniform loop
        int b0 = __shfl(b_cur, 0);
        int b8 = __shfl(b_cur, 8);
        int nb = b8 - b0;
        // coalesced: lane i holds src of local edge i (clamped tail dup)
        int sv = ssrc[min(b0 + min(lane, max(nb - 1, 0)), EE - 1)];
        int b_nxt = 0;
        if (n + nw < NN) b_nxt = offs[(n + nw) * 8 + min(lane, 8)];
#pragma unroll
        for (int t = 0; t < 4; ++t) {
            int r = 2 * t + half;
            int beg = __shfl(b_cur, r);      // full exec
            int end = __shfl(b_cur, r + 1);
            int len = end - beg;
            int mx = max(__shfl(len, 0), __shfl(len, 32));  // wave-uniform
            float a0 = 0.f, a1 = 0.f, a2 = 0.f, a3 = 0.f;
            for (int j = 0; j < mx; j += 2) {   // uniform trip: full exec
                int l0 = beg - b0 + j;
                int l1 = l0 + 1;
                int s0 = __shfl(sv, min(l0, 63));   // sources all active
                int s1 = __shfl(sv, min(l1, 63));
                if (l1 >= 64) {                 // rare: node degree > 64
                    s0 = ssrc[min(b0 + l0, EE - 1)];
                    s1 = ssrc[min(b0 + l1, EE - 1)];
                }
                uint2 q0 = h4[(size_t)s0 * 32 + sub];
                uint2 q1 = h4[(size_t)s1 * 32 + sub];
                if (j < len) {
                    a0 += bflo(q0.x); a1 += bfhi(q0.x);
                    a2 += bflo(q0.y); a3 += bfhi(q0.y);
                }
                if (j + 1 < len) {
                    a0 += bflo(q1.x); a1 += bfhi(q1.x);
                    a2 += bflo(q1.y); a3 += bfhi(q1.y);
                }
            }
            float inv = 1.0f / (float)max(len, 1);
            uint2 w;
            w.x = f2bf(a0 * inv) | (f2bf(a1 * inv) << 16);
            w.y = f2bf(a2 * inv) | (f2bf(a3 * inv) << 16);
            u4[(size_t)(n * 8 + r) * 32 + sub] = w;
        }
        b_cur = b_nxt;
    }
}

// ---------------- MFMA GEMM: out[n][o] = [u|h](n,:) @ WT(o,:)^T + bias ----------------
// Barrier-free, LDS-free (R6 post-mortem: every LDS/barrier staging variant
// throttles this latency-bound stream at 1.7-2.3 TB/s). A-fragments are 16B
// contiguous per lane in row-major u/hb -> load DIRECTLY from global; B-frags
// from L2-resident WT. Fully-unrolled K-loop: compiler register-pipelines
// dozens of independent loads; waves never synchronize.
// Wave = 32 rows x 64 cols (MT=2 amortizes B across 2 MFMAs); block = 4 waves
// = 128 rows; grid = (391, O/64).
template<bool RELU, bool OUTF32>
__global__ __launch_bounds__(256) void k_gemm(
        const ushort* __restrict__ u, const ushort* __restrict__ hb,
        const ushort* __restrict__ WT, const float* __restrict__ bias,
        void* __restrict__ outv, int O) {
    const int tid = threadIdx.x;
    const int lane = tid & 63;
    const int w = tid >> 6;
    const int m0 = blockIdx.x * 128 + w * 32;    // this wave's 32 rows
    const int o0 = blockIdx.y * 64;
    const int lr = lane & 15;                    // A-row / B-col within 16
    const int lk = (lane >> 4) * 8;              // k-octet offset
    f32x4 acc[2][4] = {};

    const ushort* arow[2];
#pragma unroll
    for (int mt = 0; mt < 2; ++mt)
        arow[mt] = u + (size_t)min(m0 + mt * 16 + lr, NN - 1) * 1024;
    const ushort* wcol[4];
#pragma unroll
    for (int nt = 0; nt < 4; ++nt)
        wcol[nt] = WT + (size_t)(o0 + nt * 16 + lr) * KTOT;

#pragma unroll
    for (int t = 0; t < 8; ++t) {                // 8 relation K-slices from u
#pragma unroll
        for (int kk = 0; kk < 4; ++kk) {
            bf16x8 a[2];
#pragma unroll
            for (int mt = 0; mt < 2; ++mt)
                a[mt] = *(const bf16x8*)(arow[mt] + t * 128 + kk * 32 + lk);
#pragma unroll
            for (int nt = 0; nt < 4; ++nt) {
                bf16x8 b = *(const bf16x8*)(wcol[nt] + t * 128 + kk * 32 + lk);
#pragma unroll
                for (int mt = 0; mt < 2; ++mt)
                    acc[mt][nt] = __builtin_amdgcn_mfma_f32_16x16x32_bf16(
                        a[mt], b, acc[mt][nt], 0, 0, 0);
            }
        }
    }
    // root K-slice from hb
#pragma unroll
    for (int kk = 0; kk < 4; ++kk) {
        bf16x8 a[2];
#pragma unroll
        for (int mt = 0; mt < 2; ++mt) {
            int n = min(m0 + mt * 16 + lr, NN - 1);
            a[mt] = *(const bf16x8*)(hb + (size_t)n * 128 + kk * 32 + lk);
        }
#pragma unroll
        for (int nt = 0; nt < 4; ++nt) {
            bf16x8 b = *(const bf16x8*)(wcol[nt] + K1 + kk * 32 + lk);
#pragma unroll
            for (int mt = 0; mt < 2; ++mt)
                acc[mt][nt] = __builtin_amdgcn_mfma_f32_16x16x32_bf16(
                    a[mt], b, acc[mt][nt], 0, 0, 0);
        }
    }
    // epilogue: C/D layout col=lane&15, row=(lane>>4)*4+j
#pragma unroll
    for (int mt = 0; mt < 2; ++mt) {
#pragma unroll
        for (int nt = 0; nt < 4; ++nt) {
            int col = o0 + nt * 16 + lr;
            float bs = bias[col];
#pragma unroll
            for (int j = 0; j < 4; ++j) {
                int row = m0 + mt * 16 + (lane >> 4) * 4 + j;
                if (row >= NN) continue;
                float v = acc[mt][nt][j] + bs;
                if (RELU) v = fmaxf(v, 0.f);
                if (OUTF32) ((float*)outv)[(size_t)row * O + col] = v;
                else ((ushort*)outv)[(size_t)row * O + col] = (ushort)f2bf(v);
            }
        }
    }
}

// ---------------- final log_softmax over 64 cols ----------------
__global__ void k_logsoftmax(const float* __restrict__ in, float* __restrict__ out) {
    int row = blockIdx.x * 4 + (threadIdx.x >> 6);
    int lane = threadIdx.x & 63;
    if (row >= NN) return;
    float v = in[(size_t)row * 64 + lane];
    float m = v;
#pragma unroll
    for (int off = 32; off; off >>= 1) m = fmaxf(m, __shfl_xor(m, off, 64));
    float e = expf(v - m);
    float s = e;
#pragma unroll
    for (int off = 32; off; off >>= 1) s += __shfl_xor(s, off, 64);
    out[(size_t)row * 64 + lane] = v - m - logf(s);
}

extern "C" void kernel_launch(void* const* d_in, const int* in_sizes, int n_in,
                              void* d_out, int out_size, void* d_ws, size_t ws_size,
                              hipStream_t stream) {
    const float* x  = (const float*)d_in[0];
    const int*   ei = (const int*)d_in[1];
    const int*   et = (const int*)d_in[2];
    const float* W[4]    = {(const float*)d_in[3], (const float*)d_in[6],
                            (const float*)d_in[9], (const float*)d_in[12]};
    const float* root[4] = {(const float*)d_in[4], (const float*)d_in[7],
                            (const float*)d_in[10], (const float*)d_in[13]};
    const float* bias[4] = {(const float*)d_in[5], (const float*)d_in[8],
                            (const float*)d_in[11], (const float*)d_in[14]};

    if (ws_size < WS_NEED) return;

    char* ws = (char*)d_ws;
    ushort* u    = (ushort*)(ws + OFF_U);
    ushort* hb0  = (ushort*)(ws + OFF_HB0);
    ushort* hb1  = (ushort*)(ws + OFF_HB1);
    ushort* xb   = (ushort*)(ws + OFF_XB);
    float*  lg   = (float*)(ws + OFF_LG);
    ushort* WT   = (ushort*)(ws + OFF_WT);
    int*   offs  = (int*)(ws + OFF_OFFS);
    int*   cur   = (int*)(ws + OFF_CUR);
    int*   ssrc  = (int*)(ws + OFF_SRT);
    int*   bsums = (int*)(ws + OFF_BS);
    ushort* WTl[4] = {WT, WT + 147456, WT + 2 * 147456, WT + 3 * 147456};

    // one-time converts
    k_cvt<<<(NN * 32 + 255) / 256, 256, 0, stream>>>(x, xb);
    k_wt<<<128, 256, 0, stream>>>(W[0], root[0], WTl[0], 128);
    k_wt<<<128, 256, 0, stream>>>(W[1], root[1], WTl[1], 128);
    k_wt<<<128, 256, 0, stream>>>(W[2], root[2], WTl[2], 128);
    k_wt<<<64,  256, 0, stream>>>(W[3], root[3], WTl[3], 64);

    // edge sort by segment key s = dst*8 + etype
    hipMemsetAsync(cur, 0, RN * sizeof(int), stream);
    k_hist<<<(EE + 255) / 256, 256, 0, stream>>>(ei, et, cur);
    k_scan1<<<NBLK, 1024, 0, stream>>>(cur, offs, bsums);
    k_scan2<<<1, 1024, 0, stream>>>(bsums);
    k_scan3<<<NBLK, 1024, 0, stream>>>(offs, bsums);
    hipMemsetAsync(cur, 0, RN * sizeof(int), stream);
    k_scatter<<<(EE + 255) / 256, 256, 0, stream>>>(ei, et, offs, cur, ssrc);

    const dim3 G2(391, 2), G1(391, 1);
    // layer 1: xb -> hb0
    k_agg<<<2048, 256, 0, stream>>>(xb, offs, ssrc, u);
    k_gemm<true, false><<<G2, 256, 0, stream>>>(u, xb, WTl[0], bias[0], hb0, 128);
    // layer 2: hb0 -> hb1
    k_agg<<<2048, 256, 0, stream>>>(hb0, offs, ssrc, u);
    k_gemm<true, false><<<G2, 256, 0, stream>>>(u, hb0, WTl[1], bias[1], hb1, 128);
    // layer 3: hb1 -> hb0
    k_agg<<<2048, 256, 0, stream>>>(hb1, offs, ssrc, u);
    k_gemm<true, false><<<G2, 256, 0, stream>>>(u, hb1, WTl[2], bias[2], hb0, 128);
    // layer 4: hb0 -> logits f32 (O=64, no relu)
    k_agg<<<2048, 256, 0, stream>>>(hb0, offs, ssrc, u);
    k_gemm<false, true><<<G1, 256, 0, stream>>>(u, hb0, WTl[3], bias[3], lg, 64);
    // log_softmax -> d_out
    k_logsoftmax<<<(NN + 3) / 4, 256, 0, stream>>>(lg, (float*)d_out);
}

// Round 8
// 579.504 us; speedup vs baseline: 1.1495x; 1.1495x over previous
//
#include <hip/hip_runtime.h>
#include <math.h>

#define NN 50000
#define RR 8
#define EE 800000
#define RN 400000            // RR * NN
#define DIN 128
#define K1 1024              // RR * DIN
#define KTOT 1152            // K1 + DIN
#define NBLK 391             // ceil(RN / 1024)

// ---------------- workspace layout (bytes) ----------------
#define OFF_U    0UL           // u bf16: [RN][128]            = 102,400,000
#define OFF_HB0  102400000UL   // h bf16: [NN][128]            =  12,800,000
#define OFF_HB1  115200000UL   // h bf16: [NN][128]            =  12,800,000
#define OFF_XB   128000000UL   // x bf16: [NN][128]            =  12,800,000
#define OFF_LG   140800000UL   // logits f32: [NN][64]         =  12,800,000
#define OFF_WT   153600000UL   // W^T bf16: 4 x 147456 elems   =   1,179,648
#define OFF_OFFS 154780160UL   // offsets: (RN+1) ints         =   1,600,128
#define OFF_CUR  156380288UL   // cursor/hist: RN ints         =   1,600,000
#define OFF_SRT  157980288UL   // sorted_src: EE ints          =   3,200,000
#define OFF_BS   161180288UL   // block sums                   =       4,096
#define WS_NEED  161184384UL

typedef short bf16x8 __attribute__((ext_vector_type(8)));
typedef float f32x4 __attribute__((ext_vector_type(4)));

__device__ __forceinline__ unsigned f2bf(float f) {       // RNE f32 -> bf16 bits
    unsigned x = __float_as_uint(f);
    return (x + 0x7fffu + ((x >> 16) & 1u)) >> 16;
}
__device__ __forceinline__ float bflo(unsigned p) { return __uint_as_float(p << 16); }
__device__ __forceinline__ float bfhi(unsigned p) { return __uint_as_float(p & 0xffff0000u); }

// ---------------- one-time converts ----------------
__global__ void k_cvt(const float* __restrict__ x, ushort* __restrict__ xb) {
    int i = blockIdx.x * 256 + threadIdx.x;
    if (i >= NN * 32) return;                 // float4 granules
    float4 v = ((const float4*)x)[i];
    ushort4 o;
    o.x = (ushort)f2bf(v.x); o.y = (ushort)f2bf(v.y);
    o.z = (ushort)f2bf(v.z); o.w = (ushort)f2bf(v.w);
    ((ushort4*)xb)[i] = o;
}

// build W^T[o][k] bf16, k in [0,1152): k<1024 -> W[k>>7][k&127][o], else root[k-1024][o]
__global__ void k_wt(const float* __restrict__ W, const float* __restrict__ Rt,
                     ushort* __restrict__ WT, int O) {
    int o = blockIdx.x;
    for (int k = threadIdx.x; k < KTOT; k += 256) {
        float v = (k < K1)
            ? W[(size_t)(k >> 7) * 128 * O + (size_t)(k & 127) * O + o]
            : Rt[(size_t)(k - K1) * O + o];
        WT[(size_t)o * KTOT + k] = (ushort)f2bf(v);
    }
}

// ---------------- edge preprocessing (counting sort by s = dst*8 + r) ----------------
__global__ void k_hist(const int* __restrict__ ei, const int* __restrict__ et,
                       int* __restrict__ hist) {
    int e = blockIdx.x * blockDim.x + threadIdx.x;
    if (e >= EE) return;
    atomicAdd(&hist[ei[EE + e] * RR + et[e]], 1);
}

__global__ void k_scan1(const int* __restrict__ hist, int* __restrict__ offs,
                        int* __restrict__ bsums) {
    __shared__ int tmp[1024];
    int tid = threadIdx.x;
    int g = blockIdx.x * 1024 + tid;
    int v = (g < RN) ? hist[g] : 0;
    tmp[tid] = v;
    __syncthreads();
    for (int off = 1; off < 1024; off <<= 1) {
        int t = tmp[tid];
        if (tid >= off) t += tmp[tid - off];
        __syncthreads();
        tmp[tid] = t;
        __syncthreads();
    }
    if (g < RN) offs[g] = tmp[tid] - v;
    if (tid == 1023) bsums[blockIdx.x] = tmp[1023];
}

__global__ void k_scan2(int* __restrict__ bsums) {
    __shared__ int tmp[1024];
    int tid = threadIdx.x;
    int v = (tid < NBLK) ? bsums[tid] : 0;
    tmp[tid] = v;
    __syncthreads();
    for (int off = 1; off < 1024; off <<= 1) {
        int t = tmp[tid];
        if (tid >= off) t += tmp[tid - off];
        __syncthreads();
        tmp[tid] = t;
        __syncthreads();
    }
    if (tid < NBLK) bsums[tid] = tmp[tid] - v;
}

__global__ void k_scan3(int* __restrict__ offs, const int* __restrict__ bsums) {
    int g = blockIdx.x * 1024 + threadIdx.x;
    if (g < RN) offs[g] += bsums[blockIdx.x];
    else if (g == RN) offs[RN] = EE;
}

__global__ void k_scatter(const int* __restrict__ ei, const int* __restrict__ et,
                          const int* __restrict__ offs, int* __restrict__ cur,
                          int* __restrict__ ssrc) {
    int e = blockIdx.x * blockDim.x + threadIdx.x;
    if (e >= EE) return;
    int s = ei[EE + e] * RR + et[e];
    ssrc[offs[s] + atomicAdd(&cur[s], 1)] = ei[e];
}

// ---------------- per-layer segment mean aggregation ----------------
// wave <-> node; all 8 segments of node n are contiguous in ssrc.
// One coalesced ssrc read into registers; edge srcs broadcast via __shfl.
// SAFETY INVARIANT (ds_bpermute returns UNDEFINED from exec=0 lanes): every
// __shfl here executes at FULL wave exec — the edge loop trip count is
// wave-uniform (max over the half-wave pair), shfl indices are clamped to
// [0,63], and per-lane validity only guards the VALU accumulates.
__global__ __launch_bounds__(256) void k_agg(const ushort* __restrict__ hb,
        const int* __restrict__ offs, const int* __restrict__ ssrc,
        ushort* __restrict__ u) {
    int gt = blockIdx.x * 256 + threadIdx.x;
    int wid = gt >> 6, lane = gt & 63;
    int nw = (gridDim.x * 256) >> 6;
    int half = lane >> 5;                    // 0/1: which segment of the pair
    int sub = lane & 31;                     // cols [4*sub, 4*sub+4)
    const uint2* h4 = (const uint2*)hb;
    uint2* u4 = (uint2*)u;

    if (wid >= NN) return;                   // wave-uniform
    int b_cur = offs[wid * 8 + min(lane, 8)];
    for (int n = wid; n < NN; n += nw) {     // wave-uniform loop
        int b0 = __shfl(b_cur, 0);
        int b8 = __shfl(b_cur, 8);
        int nb = b8 - b0;
        // coalesced: lane i holds src of local edge i (clamped tail dup)
        int sv = ssrc[min(b0 + min(lane, max(nb - 1, 0)), EE - 1)];
        int b_nxt = 0;
        if (n + nw < NN) b_nxt = offs[(n + nw) * 8 + min(lane, 8)];
#pragma unroll
        for (int t = 0; t < 4; ++t) {
            int r = 2 * t + half;
            int beg = __shfl(b_cur, r);      // full exec
            int end = __shfl(b_cur, r + 1);
            int len = end - beg;
            int mx = max(__shfl(len, 0), __shfl(len, 32));  // wave-uniform
            float a0 = 0.f, a1 = 0.f, a2 = 0.f, a3 = 0.f;
            for (int j = 0; j < mx; j += 2) {   // uniform trip: full exec
                int l0 = beg - b0 + j;
                int l1 = l0 + 1;
                int s0 = __shfl(sv, min(l0, 63));   // sources all active
                int s1 = __shfl(sv, min(l1, 63));
                if (l1 >= 64) {                 // rare: node degree > 64
                    s0 = ssrc[min(b0 + l0, EE - 1)];
                    s1 = ssrc[min(b0 + l1, EE - 1)];
                }
                uint2 q0 = h4[(size_t)s0 * 32 + sub];
                uint2 q1 = h4[(size_t)s1 * 32 + sub];
                if (j < len) {
                    a0 += bflo(q0.x); a1 += bfhi(q0.x);
                    a2 += bflo(q0.y); a3 += bfhi(q0.y);
                }
                if (j + 1 < len) {
                    a0 += bflo(q1.x); a1 += bfhi(q1.x);
                    a2 += bflo(q1.y); a3 += bfhi(q1.y);
                }
            }
            float inv = 1.0f / (float)max(len, 1);
            uint2 w;
            w.x = f2bf(a0 * inv) | (f2bf(a1 * inv) << 16);
            w.y = f2bf(a2 * inv) | (f2bf(a3 * inv) << 16);
            u4[(size_t)(n * 8 + r) * 32 + sub] = w;
        }
        b_cur = b_nxt;
    }
}

// ---------------- MFMA GEMM: out[n][o] = [u|h](n,:) @ WT(o,:)^T + bias ----------------
// R5 structure (best measured: bulk regs[4] staging = 1024 loads/block in
// flight under MFMA) with ONE change: LDS double-buffer -> 1 barrier/K-step
// instead of 2. Race audit: barrier at end of iter t-1 guarantees (a) all
// stores into buf[t&1] (done in iter t-1) visible before mma(t) reads it,
// (b) all reads of buf[(t+1)&1] (mma in iter t-1) done before storeA
// overwrites it in iter t. BM=64, BN=128 (A read once), grid 782.
template<int NT, bool RELU, bool OUTF32>
__global__ __launch_bounds__(256) void k_gemm(
        const ushort* __restrict__ u, const ushort* __restrict__ hb,
        const ushort* __restrict__ WT, const float* __restrict__ bias,
        void* __restrict__ outv) {
    constexpr int BN = 4 * NT * 16;
    __shared__ ushort As[2][64 * 128];       // 16 KB x 2
    const int tid = threadIdx.x;
    const int lane = tid & 63;
    const int wc = tid >> 6;                 // 4 waves side-by-side in cols
    const int m0 = blockIdx.x * 64;
    f32x4 acc[4][NT] = {};
    uint4 regs[4];

    auto loadA = [&](int t) {
#pragma unroll
        for (int i = 0; i < 4; ++i) {
            int c = i * 256 + tid;           // chunk id: (row, g)
            int row = c >> 4, g = c & 15;
            int nn = min(m0 + row, NN - 1);
            const ushort* p = (t < 8) ? u + (size_t)nn * 1024 + t * 128 + g * 8
                                      : hb + (size_t)nn * 128 + g * 8;
            regs[i] = *(const uint4*)p;
        }
    };
    auto storeA = [&](int buf) {
#pragma unroll
        for (int i = 0; i < 4; ++i) {
            int c = i * 256 + tid;
            int row = c >> 4, g = c & 15;
            *(uint4*)(&As[buf][row * 128 + ((g ^ (row & 15)) * 8)]) = regs[i];
        }
    };
    auto mma = [&](int t, int buf) {
#pragma unroll
        for (int kk = 0; kk < 4; ++kk) {
            bf16x8 bfr[NT];
#pragma unroll
            for (int nt = 0; nt < NT; ++nt) {
                int col = wc * NT * 16 + nt * 16 + (lane & 15);
                int k = t * 128 + kk * 32 + (lane >> 4) * 8;
                bfr[nt] = *(const bf16x8*)(WT + (size_t)col * KTOT + k);
            }
#pragma unroll
            for (int mt = 0; mt < 4; ++mt) {
                int row = mt * 16 + (lane & 15);
                int g = kk * 4 + (lane >> 4);
                bf16x8 a = *(const bf16x8*)(&As[buf][row * 128 + ((g ^ (row & 15)) * 8)]);
#pragma unroll
                for (int nt = 0; nt < NT; ++nt)
                    acc[mt][nt] = __builtin_amdgcn_mfma_f32_16x16x32_bf16(
                        a, bfr[nt], acc[mt][nt], 0, 0, 0);
            }
        }
    };

    loadA(0);
    storeA(0);
    __syncthreads();
    for (int t = 0; t < 9; ++t) {
        if (t < 8) loadA(t + 1);             // bulk loads fly under MFMA
        mma(t, t & 1);
        if (t < 8) storeA((t + 1) & 1);      // other buffer: no reader clash
        __syncthreads();
    }
#pragma unroll
    for (int mt = 0; mt < 4; ++mt) {
#pragma unroll
        for (int nt = 0; nt < NT; ++nt) {
            int col = wc * NT * 16 + nt * 16 + (lane & 15);
            float bs = bias[col];
#pragma unroll
            for (int j = 0; j < 4; ++j) {
                int row = m0 + mt * 16 + (lane >> 4) * 4 + j;
                if (row >= NN) continue;
                float v = acc[mt][nt][j] + bs;
                if (RELU) v = fmaxf(v, 0.f);
                if (OUTF32) ((float*)outv)[(size_t)row * BN + col] = v;
                else ((ushort*)outv)[(size_t)row * BN + col] = (ushort)f2bf(v);
            }
        }
    }
}

// ---------------- final log_softmax over 64 cols ----------------
__global__ void k_logsoftmax(const float* __restrict__ in, float* __restrict__ out) {
    int row = blockIdx.x * 4 + (threadIdx.x >> 6);
    int lane = threadIdx.x & 63;
    if (row >= NN) return;
    float v = in[(size_t)row * 64 + lane];
    float m = v;
#pragma unroll
    for (int off = 32; off; off >>= 1) m = fmaxf(m, __shfl_xor(m, off, 64));
    float e = expf(v - m);
    float s = e;
#pragma unroll
    for (int off = 32; off; off >>= 1) s += __shfl_xor(s, off, 64);
    out[(size_t)row * 64 + lane] = v - m - logf(s);
}

extern "C" void kernel_launch(void* const* d_in, const int* in_sizes, int n_in,
                              void* d_out, int out_size, void* d_ws, size_t ws_size,
                              hipStream_t stream) {
    const float* x  = (const float*)d_in[0];
    const int*   ei = (const int*)d_in[1];
    const int*   et = (const int*)d_in[2];
    const float* W[4]    = {(const float*)d_in[3], (const float*)d_in[6],
                            (const float*)d_in[9], (const float*)d_in[12]};
    const float* root[4] = {(const float*)d_in[4], (const float*)d_in[7],
                            (const float*)d_in[10], (const float*)d_in[13]};
    const float* bias[4] = {(const float*)d_in[5], (const float*)d_in[8],
                            (const float*)d_in[11], (const float*)d_in[14]};

    if (ws_size < WS_NEED) return;

    char* ws = (char*)d_ws;
    ushort* u    = (ushort*)(ws + OFF_U);
    ushort* hb0  = (ushort*)(ws + OFF_HB0);
    ushort* hb1  = (ushort*)(ws + OFF_HB1);
    ushort* xb   = (ushort*)(ws + OFF_XB);
    float*  lg   = (float*)(ws + OFF_LG);
    ushort* WT   = (ushort*)(ws + OFF_WT);
    int*   offs  = (int*)(ws + OFF_OFFS);
    int*   cur   = (int*)(ws + OFF_CUR);
    int*   ssrc  = (int*)(ws + OFF_SRT);
    int*   bsums = (int*)(ws + OFF_BS);
    ushort* WTl[4] = {WT, WT + 147456, WT + 2 * 147456, WT + 3 * 147456};

    // one-time converts
    k_cvt<<<(NN * 32 + 255) / 256, 256, 0, stream>>>(x, xb);
    k_wt<<<128, 256, 0, stream>>>(W[0], root[0], WTl[0], 128);
    k_wt<<<128, 256, 0, stream>>>(W[1], root[1], WTl[1], 128);
    k_wt<<<128, 256, 0, stream>>>(W[2], root[2], WTl[2], 128);
    k_wt<<<64,  256, 0, stream>>>(W[3], root[3], WTl[3], 64);

    // edge sort by segment key s = dst*8 + etype
    hipMemsetAsync(cur, 0, RN * sizeof(int), stream);
    k_hist<<<(EE + 255) / 256, 256, 0, stream>>>(ei, et, cur);
    k_scan1<<<NBLK, 1024, 0, stream>>>(cur, offs, bsums);
    k_scan2<<<1, 1024, 0, stream>>>(bsums);
    k_scan3<<<NBLK, 1024, 0, stream>>>(offs, bsums);
    hipMemsetAsync(cur, 0, RN * sizeof(int), stream);
    k_scatter<<<(EE + 255) / 256, 256, 0, stream>>>(ei, et, offs, cur, ssrc);

    const int G = (NN + 63) / 64;   // 782
    // layer 1: xb -> hb0
    k_agg<<<2048, 256, 0, stream>>>(xb, offs, ssrc, u);
    k_gemm<2, true, false><<<G, 256, 0, stream>>>(u, xb, WTl[0], bias[0], hb0);
    // layer 2: hb0 -> hb1
    k_agg<<<2048, 256, 0, stream>>>(hb0, offs, ssrc, u);
    k_gemm<2, true, false><<<G, 256, 0, stream>>>(u, hb0, WTl[1], bias[1], hb1);
    // layer 3: hb1 -> hb0
    k_agg<<<2048, 256, 0, stream>>>(hb1, offs, ssrc, u);
    k_gemm<2, true, false><<<G, 256, 0, stream>>>(u, hb1, WTl[2], bias[2], hb0);
    // layer 4: hb0 -> logits f32 (O=64, no relu)
    k_agg<<<2048, 256, 0, stream>>>(hb0, offs, ssrc, u);
    k_gemm<1, false, true><<<G, 256, 0, stream>>>(u, hb0, WTl[3], bias[3], lg);
    // log_softmax -> d_out
    k_logsoftmax<<<(NN + 3) / 4, 256, 0, stream>>>(lg, (float*)d_out);
}